// Round 1
// baseline (73.999 us; speedup 1.0000x reference)
//
#include <hip/hip_runtime.h>

// EWMA scan: y_t = (1-alpha) * y_{t-1} + alpha * x_t, y_{-1} = first_offset.
// Chunked parallel scan: L split into C chunks of T. Phase1 computes per-chunk
// local scans' end values; phase2 does the inter-chunk scan (one wave per
// column, Kogge-Stone over lanes); phase3 recomputes local scans and adds the
// decayed carry, writing the full output + last row.

#define LT  32768
#define DC  1024
#define TCH 64              // timesteps per chunk
#define CCH (LT / TCH)      // 512 chunks
#define TPB 256
#define D4  (DC / 4)        // 256 float4 per row

__global__ void ewma_phase1(const float4* __restrict__ data4,
                            float4* __restrict__ zend4,
                            const float* __restrict__ alpha_p) {
    const float alpha = alpha_p[0];
    const float decay = 1.0f - alpha;
    const int tid = threadIdx.x;    // float4 column group
    const int c = blockIdx.x;       // chunk index
    const float4* p = data4 + (size_t)c * TCH * D4 + tid;
    float z0 = 0.f, z1 = 0.f, z2 = 0.f, z3 = 0.f;
#pragma unroll 8
    for (int i = 0; i < TCH; ++i) {
        float4 x = p[(size_t)i * D4];
        z0 = fmaf(decay, z0, alpha * x.x);
        z1 = fmaf(decay, z1, alpha * x.y);
        z2 = fmaf(decay, z2, alpha * x.z);
        z3 = fmaf(decay, z3, alpha * x.w);
    }
    zend4[c * D4 + tid] = make_float4(z0, z1, z2, z3);
}

// One wave per column d. Lane l owns chunks [l*CPL, (l+1)*CPL).
// Inter-chunk recurrence: S_c(end) = r * S_{c-1}(end) + e_c, r = decay^TCH.
__global__ void ewma_phase2(const float* __restrict__ zend,
                            const float* __restrict__ first,
                            float* __restrict__ carry,
                            const float* __restrict__ alpha_p) {
    const float alpha = alpha_p[0];
    const float decay = 1.0f - alpha;
    float r = 1.0f;
    for (int i = 0; i < TCH; ++i) r *= decay;   // decay^TCH

    const int lane = threadIdx.x & 63;
    const int wave = (blockIdx.x * blockDim.x + threadIdx.x) >> 6;  // = column d
    const int d = wave;
    constexpr int CPL = CCH / 64;   // 8 chunks per lane

    float e[CPL];
#pragma unroll
    for (int j = 0; j < CPL; ++j)
        e[j] = zend[(lane * CPL + j) * DC + d];

    // lane-local aggregate: A = scan of e over CPL chunks with ratio r, zero init
    float A = 0.f;
#pragma unroll
    for (int j = 0; j < CPL; ++j) A = fmaf(r, A, e[j]);

    // q = r^CPL (ratio between consecutive lane aggregates)
    float q = 1.f;
    for (int j = 0; j < CPL; ++j) q *= r;

    // Kogge-Stone inclusive scan across 64 lanes: y_l = A_l + q * y_{l-1}
    float y = A;
    float p = q;
#pragma unroll
    for (int o = 1; o < 64; o <<= 1) {
        float prev = __shfl_up(y, o, 64);
        if (lane >= o) y = fmaf(p, prev, y);
        p = p * p;
    }
    // exclusive: value at end of lane (l-1)'s chunks, zero-init part
    float excl = __shfl_up(y, 1, 64);
    if (lane == 0) excl = 0.f;

    // decayed first_offset contribution: q^lane
    float qpow = 1.f;
    {
        float base = q;
        int e2 = lane;
        while (e2) { if (e2 & 1) qpow *= base; base *= base; e2 >>= 1; }
    }
    float S = fmaf(qpow, first[d], excl);  // y_{start-1} for this lane's first chunk

#pragma unroll
    for (int j = 0; j < CPL; ++j) {
        const int c = lane * CPL + j;
        carry[c * DC + d] = S;         // carry-in for chunk c
        S = fmaf(r, S, e[j]);
    }
}

__global__ void ewma_phase3(const float4* __restrict__ data4,
                            const float4* __restrict__ carry4,
                            float4* __restrict__ out4,
                            float4* __restrict__ out_last4,
                            const float* __restrict__ alpha_p) {
    const float alpha = alpha_p[0];
    const float decay = 1.0f - alpha;
    const int tid = threadIdx.x;
    const int c = blockIdx.x;
    const float4 cin = carry4[c * D4 + tid];
    const float4* p = data4 + (size_t)c * TCH * D4 + tid;
    float4* o = out4 + (size_t)c * TCH * D4 + tid;
    float z0 = 0.f, z1 = 0.f, z2 = 0.f, z3 = 0.f, pw = 1.f;
#pragma unroll 8
    for (int i = 0; i < TCH; ++i) {
        float4 x = p[(size_t)i * D4];
        z0 = fmaf(decay, z0, alpha * x.x);
        z1 = fmaf(decay, z1, alpha * x.y);
        z2 = fmaf(decay, z2, alpha * x.z);
        z3 = fmaf(decay, z3, alpha * x.w);
        pw *= decay;
        float4 yv;
        yv.x = fmaf(pw, cin.x, z0);
        yv.y = fmaf(pw, cin.y, z1);
        yv.z = fmaf(pw, cin.z, z2);
        yv.w = fmaf(pw, cin.w, z3);
        o[(size_t)i * D4] = yv;
    }
    if (c == CCH - 1) {
        float4 yl;
        yl.x = fmaf(pw, cin.x, z0);
        yl.y = fmaf(pw, cin.y, z1);
        yl.z = fmaf(pw, cin.z, z2);
        yl.w = fmaf(pw, cin.w, z3);
        out_last4[tid] = yl;
    }
}

extern "C" void kernel_launch(void* const* d_in, const int* in_sizes, int n_in,
                              void* d_out, int out_size, void* d_ws, size_t ws_size,
                              hipStream_t stream) {
    const float* data    = (const float*)d_in[0];
    const float* first   = (const float*)d_in[1];
    const float* alpha_p = (const float*)d_in[2];
    float* out = (float*)d_out;

    float* zend  = (float*)d_ws;              // CCH*DC floats = 2 MB
    float* carry = zend + (size_t)CCH * DC;   // CCH*DC floats = 2 MB

    ewma_phase1<<<CCH, TPB, 0, stream>>>(
        (const float4*)data, (float4*)zend, alpha_p);

    ewma_phase2<<<DC / (TPB / 64), TPB, 0, stream>>>(
        zend, first, carry, alpha_p);

    ewma_phase3<<<CCH, TPB, 0, stream>>>(
        (const float4*)data, (const float4*)carry, (float4*)out,
        (float4*)(out + (size_t)LT * DC), alpha_p);
}